// Round 2
// baseline (662.830 us; speedup 1.0000x reference)
//
#include <hip/hip_runtime.h>

// Problem constants (from reference)
#define B_      4
#define N_      200000
#define C_      96
#define S_      32
#define EPS_    1e-5f

#define C4      (C_ / 4)          // 24 float4 per point
#define NC4     (N_ * C4)         // 4,800,000 float4 per batch
#define THREADS 256
#define ITER    75                // 256*75 = 19200 f4/chunk; 250 chunks/batch exactly
#define CHUNK   (THREADS * ITER)  // 19200
#define BLK_X   (NC4 / CHUNK)     // 250 (exact, no tail)
#define NBLK    (BLK_X * B_)      // 1000 blocks total — MUST be <= 1024 co-resident
#define GROUPS  (ITER / 3)        // 25 (period-3 channel phase)

typedef float f32x4 __attribute__((ext_vector_type(4)));

__device__ __forceinline__ float4 scale4(const float4 a, const float s) {
    return make_float4(a.x * s, a.y * s, a.z * s, a.w * s);
}
__device__ __forceinline__ float4 nms4(const float4 bb, const float m, const float4 fw) {
    return make_float4(bb.x - m * fw.x, bb.y - m * fw.y, bb.z - m * fw.z, bb.w - m * fw.w);
}

// ---------------------------------------------------------------------------
// Single fused kernel. 1000 persistent blocks (4 blocks/CU guaranteed by
// __launch_bounds__(256,4) -> <=128 VGPR -> capacity 1024 >= 1000, so the
// software grid barrier cannot deadlock).
//
// Phase 1: per-block segment partial sums (incremental (n,c,sg) tracking from
//          the 33-entry offsets table; no gathers, no per-element division).
// Barrier: device-scope atomic counter. Spin uses atomic RMW reads only —
//          plain loads can be served stale forever by the non-coherent
//          per-XCD L2s.
// Finalize: each block derives all 32 (mean, rstd) of its batch from the
//          global accumulators, read back via atomicAdd(p, 0.f) (coherent).
// Phase 2: re-read own chunk DESCENDING (tail was read just before the
//          barrier -> L3-resident, newest-first), fold (x-m)*r*w+b into
//          x*fw+fb with 3 register-cached pairs, nontemporal stores for out.
// ---------------------------------------------------------------------------
__global__ __launch_bounds__(THREADS, 4) void fused_kernel(
    const float4* __restrict__ x,
    const int*    __restrict__ offsets,   // [S+1]
    const float4* __restrict__ wgt,       // [24]
    const float4* __restrict__ bia,       // [24]
    float*        __restrict__ gsum,      // ws: [B*S]
    float*        __restrict__ gsq,       // ws: [B*S]
    int*          __restrict__ cnt,       // ws: barrier counter (memset to 0)
    float4*       __restrict__ out)
{
    __shared__ int    soff[S_ + 1];
    __shared__ float  lsum[S_], lsq[S_];
    __shared__ float4 lw[C4], lb[C4];
    __shared__ float  lm[S_], lr[S_];

    const int t = threadIdx.x;
    const int b = blockIdx.y;

    if (t <= S_) soff[t] = offsets[t];
    if (t <  S_) { lsum[t] = 0.f; lsq[t] = 0.f; }
    if (t <  C4) { lw[t] = wgt[t]; lb[t] = bia[t]; }
    __syncthreads();

    const float4* xb = x + (size_t)b * NC4;
    const int f0 = blockIdx.x * CHUNK + t;

    // ---- Phase 1: stats ----------------------------------------------------
    int n = f0 / 24;                 // one division per thread total
    const int cstart = f0 - n * 24;  // channel-quad phase at k=0
    int c = cstart;

    int sg = 0;
    #pragma unroll
    for (int st = 16; st; st >>= 1) {
        const int cand = sg + st;    // cand <= 31 always
        if (soff[cand] <= n) sg = cand;
    }
    int nxt = soff[sg + 1];

    float s1 = 0.f, s2 = 0.f;
    for (int k = 0; k < ITER; ++k) {
        if (n >= nxt) {                          // rare: segment boundary
            atomicAdd(&lsum[sg], s1);
            atomicAdd(&lsq [sg], s2);
            s1 = 0.f; s2 = 0.f;
            do { ++sg; } while (soff[sg + 1] <= n);   // soff[32]=N stops
            nxt = soff[sg + 1];
        }
        const float4 v = xb[f0 + k * THREADS];
        s1 += (v.x + v.y) + (v.z + v.w);
        s2 += v.x * v.x + v.y * v.y + v.z * v.z + v.w * v.w;
        c += 16; if (c >= 24) { c -= 24; ++n; }  // +256 f4 = +10 pts +16 quads
        n += 10;
    }
    atomicAdd(&lsum[sg], s1);
    atomicAdd(&lsq [sg], s2);
    __syncthreads();

    if (t < S_) {
        const float a = lsum[t];
        const float q = lsq[t];
        if (a != 0.f || q != 0.f) {              // accumulators pre-zeroed
            atomicAdd(&gsum[b * S_ + t], a);
            atomicAdd(&gsq [b * S_ + t], q);
        }
    }

    // ---- Grid barrier ------------------------------------------------------
    __syncthreads();                 // drains this block's atomics (vmcnt 0)
    if (t == 0) {
        __threadfence();
        atomicAdd(cnt, 1);
        while (atomicAdd(cnt, 0) < NBLK) __builtin_amdgcn_s_sleep(16);
    }
    __syncthreads();

    // ---- Finalize (per block, its batch's 32 segments) ---------------------
    if (t < S_) {
        const float s1g = atomicAdd(&gsum[b * S_ + t], 0.f);  // coherent read
        const float s2g = atomicAdd(&gsq [b * S_ + t], 0.f);
        const float cf  = (float)(soff[t + 1] - soff[t]) * (float)C_;
        const float m   = s1g / cf;
        const float v   = s2g / cf - m * m;
        lm[t] = m;
        lr[t] = rsqrtf(fmaxf(v, 0.f) + EPS_);
    }
    __syncthreads();

    // ---- Phase 2: normalize own chunk, descending --------------------------
    float4* ob = out + (size_t)b * NC4;

    // phase classes: k%3==0 -> c0, ==1 -> c1, ==2 -> c2
    const int c0 = cstart;
    int c1 = c0 + 16; if (c1 >= 24) c1 -= 24;
    int c2 = c0 + 8;  if (c2 >= 24) c2 -= 24;

    const int fhi = f0 + (ITER - 1) * THREADS;
    n = fhi / 24;
    c = fhi - n * 24;

    sg = 0;
    #pragma unroll
    for (int st = 16; st; st >>= 1) {
        const int cand = sg + st;
        if (soff[cand] <= n) sg = cand;
    }
    int lo = soff[sg];

    float4 fw0, fb0, fw1, fb1, fw2, fb2;
#define RECOMP() { \
        const float m_ = lm[sg], r_ = lr[sg]; \
        fw0 = scale4(lw[c0], r_); fb0 = nms4(lb[c0], m_, fw0); \
        fw1 = scale4(lw[c1], r_); fb1 = nms4(lb[c1], m_, fw1); \
        fw2 = scale4(lw[c2], r_); fb2 = nms4(lb[c2], m_, fw2); \
    }
    RECOMP();

#define NBODY(K, J) { \
        if (n < lo) {                                   /* rare */ \
            do { --sg; } while (n < soff[sg]);          /* soff[0]=0 stops */ \
            lo = soff[sg]; \
            RECOMP(); \
        } \
        const int fi = f0 + (K) * THREADS; \
        const float4 v = xb[fi]; \
        float4 o; \
        o.x = v.x * fw##J.x + fb##J.x; \
        o.y = v.y * fw##J.y + fb##J.y; \
        o.z = v.z * fw##J.z + fb##J.z; \
        o.w = v.w * fw##J.w + fb##J.w; \
        __builtin_nontemporal_store(*(const f32x4*)&o, (f32x4*)(ob + fi)); \
        c -= 16; if (c < 0) { c += 24; --n; } \
        n -= 10; \
    }

    for (int g = GROUPS - 1; g >= 0; --g) {
        NBODY(3 * g + 2, 2)
        NBODY(3 * g + 1, 1)
        NBODY(3 * g + 0, 0)
    }
#undef NBODY
#undef RECOMP
}

// ---------------------------------------------------------------------------
extern "C" void kernel_launch(void* const* d_in, const int* in_sizes, int n_in,
                              void* d_out, int out_size, void* d_ws, size_t ws_size,
                              hipStream_t stream)
{
    const float* x       = (const float*)d_in[0];
    const int*   offsets = (const int*)  d_in[1];
    const int*   indices = (const int*)  d_in[2];   // unused (offsets suffice)
    const float* weight  = (const float*)d_in[3];
    const float* bias    = (const float*)d_in[4];
    float*       out     = (float*)d_out;
    (void)indices; (void)in_sizes; (void)n_in; (void)out_size; (void)ws_size;

    float* gsum = (float*)d_ws;          // [128]
    float* gsq  = gsum + B_ * S_;        // [128]
    int*   cnt  = (int*)(gsq + B_ * S_); // barrier counter

    // ws is poisoned before every timed call (and before every rocprof
    // replay); this memset re-runs each replay too, so the accumulators and
    // barrier counter always start at 0. ~1KB -> a few microseconds.
    hipMemsetAsync(d_ws, 0, (2 * B_ * S_ + 1) * sizeof(float), stream);

    dim3 grid(BLK_X, B_);                // 250 x 4 = 1000 blocks, all resident
    fused_kernel<<<grid, THREADS, 0, stream>>>(
        (const float4*)x, offsets, (const float4*)weight, (const float4*)bias,
        gsum, gsq, cnt, (float4*)out);
}